// Round 1
// baseline (1690.328 us; speedup 1.0000x reference)
//
#include <hip/hip_runtime.h>

#define NBATCH 32
#define CHAN   512
#define HWSZ   4096
#define NG     8
#define NM     64
#define MTOT   (NBATCH * HWSZ)   // 131072 samples per channel
#define EPSC   0.01f

// ---------------------------------------------------------------------------
// Kernel 1: raw Gram (x x^T) per group + per-channel sums.
// Grid: 1024 blocks = 8 groups x 32 batch x 4 hw-quarters. Block: 256.
// LDS tile: [64 pos][64 ch] fp32 with float4-group XOR swizzle so that
//  - compute reads (b128 at uniform pos) are bank-conflict-free
//  - transpose writes are ~8-way (small fraction of tile cycles)
// ---------------------------------------------------------------------------
__global__ __launch_bounds__(256) void gram_k(const float* __restrict__ x,
                                              float* __restrict__ gram,
                                              float* __restrict__ sums) {
    __shared__ float tile[64 * 64];

    const int bid = blockIdx.x;      // 0..1023
    const int g   = bid >> 7;        // 0..7
    const int blk = bid & 127;       // 0..127
    const int n   = blk >> 2;        // 0..31
    const int q   = blk & 3;         // 0..3  (hw quarter)
    const float* xb = x + ((size_t)(n * CHAN + g * NM)) * HWSZ + q * 1024;

    const int t    = threadIdx.x;
    const int pos4 = t & 15;         // loader: float4-group over positions
    const int chb  = t >> 4;         // loader: base channel (0..15)
    const int ty   = t >> 4;         // compute: row block  (i0 = ty*4)
    const int tx   = t & 15;         // compute: col block  (j0 = tx*4)

    float acc[4][4];
#pragma unroll
    for (int a = 0; a < 4; ++a)
#pragma unroll
        for (int b = 0; b < 4; ++b) acc[a][b] = 0.f;
    float fsum[4] = {0.f, 0.f, 0.f, 0.f};

    for (int tt = 0; tt < 16; ++tt) {
        const float* xt = xb + tt * 64;
#pragma unroll
        for (int r = 0; r < 4; ++r) {
            const int ch = chb + 16 * r;
            const float4 v = *(const float4*)(xt + (size_t)ch * HWSZ + pos4 * 4);
            fsum[r] += v.x + v.y + v.z + v.w;
            const int p0 = pos4 * 4;
            const int c4 = ch >> 2, cl = ch & 3;
            tile[(p0 + 0) * 64 + ((c4 ^ ((p0 + 0) & 15)) << 2) + cl] = v.x;
            tile[(p0 + 1) * 64 + ((c4 ^ ((p0 + 1) & 15)) << 2) + cl] = v.y;
            tile[(p0 + 2) * 64 + ((c4 ^ ((p0 + 2) & 15)) << 2) + cl] = v.z;
            tile[(p0 + 3) * 64 + ((c4 ^ ((p0 + 3) & 15)) << 2) + cl] = v.w;
        }
        __syncthreads();

#pragma unroll 16
        for (int m = 0; m < 64; ++m) {
            const float4 a4 = *(const float4*)&tile[m * 64 + ((ty ^ (m & 15)) << 2)];
            const float4 b4 = *(const float4*)&tile[m * 64 + ((tx ^ (m & 15)) << 2)];
            const float av[4] = {a4.x, a4.y, a4.z, a4.w};
            const float bv[4] = {b4.x, b4.y, b4.z, b4.w};
#pragma unroll
            for (int ai = 0; ai < 4; ++ai)
#pragma unroll
                for (int bi = 0; bi < 4; ++bi)
                    acc[ai][bi] = fmaf(av[ai], bv[bi], acc[ai][bi]);
        }
        __syncthreads();
    }

    float* gg = gram + g * 4096;
#pragma unroll
    for (int ai = 0; ai < 4; ++ai)
#pragma unroll
        for (int bi = 0; bi < 4; ++bi)
            atomicAdd(&gg[(ty * 4 + ai) * 64 + tx * 4 + bi], acc[ai][bi]);
#pragma unroll
    for (int r = 0; r < 4; ++r)
        atomicAdd(&sums[g * NM + chb + 16 * r], fsum[r]);
}

// ---------------------------------------------------------------------------
// Kernel 2: per-group (8 blocks) inverse matrix sqrt via [5/5] Pade + GJ solve.
//   cov = Gram/M - mu mu^T + eps I
//   p_app = I - cov/||cov||_F ; P = sum pp_k p_app^k ; Q = sum qq_k p_app^k
//   subspace = P^{-1} Q / sqrt(||cov||_F)
//   Tt[j][i] = subspace[i][j]*w[i];  off[i] = bias[i] - w[i]*sum_j S[i][j]mu[j]
// Pade coeffs closed form: A(x)=sum binom(11,2k)(1-x)^k, B(x)=binom(11,2k+1)...
// expanded in powers of x, /1024 (verified against reference linear system).
// ---------------------------------------------------------------------------
__global__ __launch_bounds__(256) void solve_k(const float* __restrict__ gram,
                                               const float* __restrict__ sums,
                                               const float* __restrict__ wgt,
                                               const float* __restrict__ bias,
                                               float* __restrict__ Tt,
                                               float* __restrict__ offv) {
    __shared__ float A[4096];   // p_app, later P
    __shared__ float B[4096];   // ph ping, later Q (becomes P^{-1}Q)
    __shared__ float Cc[4096];  // ph pong
    __shared__ float mus[64];
    __shared__ float red[4];

    const int g = blockIdx.x, t = threadIdx.x;
    const float* gg = gram + g * 4096;

    if (t < 64) mus[t] = sums[g * NM + t] * (1.0f / MTOT);
    __syncthreads();

    // covariance + local norm partial
    float covv[16];
    float loc = 0.f;
#pragma unroll
    for (int k = 0; k < 16; ++k) {
        const int e = t + 256 * k;
        const int i = e >> 6, j = e & 63;
        float cv = gg[e] * (1.0f / MTOT) - mus[i] * mus[j] + (i == j ? EPSC : 0.f);
        covv[k] = cv;
        loc += cv * cv;
    }
#pragma unroll
    for (int o = 32; o > 0; o >>= 1) loc += __shfl_down(loc, o);
    if ((t & 63) == 0) red[t >> 6] = loc;
    __syncthreads();
    const float normM = sqrtf(red[0] + red[1] + red[2] + red[3]);
    const float ninv  = 1.0f / normM;

#pragma unroll
    for (int k = 0; k < 16; ++k) {
        const int e = t + 256 * k;
        const int i = e >> 6, j = e & 63;
        const float pa = (i == j ? 1.f : 0.f) - covv[k] * ninv;
        A[e] = pa;
        B[e] = pa;  // ph = p_app
    }
    __syncthreads();

    const int ty = t >> 4, tx = t & 15;
    const int i0 = ty * 4, j0 = tx * 4;

    const float PP[6] = {1.f, -2.75f, 2.75f, -1.203125f, 0.21484375f, -0.0107421875f};
    const float QQ[6] = {1.f, -2.25f, 1.75f, -0.546875f, 0.05859375f, -0.0009765625f};

    float pacc[4][4], qacc[4][4];
#pragma unroll
    for (int ai = 0; ai < 4; ++ai)
#pragma unroll
        for (int bi = 0; bi < 4; ++bi) {
            const int i = i0 + ai, j = j0 + bi;
            const float pa = A[i * 64 + j];
            const float id = (i == j) ? 1.f : 0.f;
            pacc[ai][bi] = PP[0] * id + PP[1] * pa;
            qacc[ai][bi] = QQ[0] * id + QQ[1] * pa;
        }

    float* src = B;
    float* dst = Cc;
    for (int s = 0; s < 4; ++s) {
        float mm[4][4];
#pragma unroll
        for (int ai = 0; ai < 4; ++ai)
#pragma unroll
            for (int bi = 0; bi < 4; ++bi) mm[ai][bi] = 0.f;
        // dst = src @ p_app  (src symmetric: src[i][k] = src[k][i])
        for (int kk = 0; kk < 64; ++kk) {
            const float4 a4 = *(const float4*)&src[kk * 64 + i0];
            const float4 b4 = *(const float4*)&A[kk * 64 + j0];
            const float av[4] = {a4.x, a4.y, a4.z, a4.w};
            const float bv[4] = {b4.x, b4.y, b4.z, b4.w};
#pragma unroll
            for (int ai = 0; ai < 4; ++ai)
#pragma unroll
                for (int bi = 0; bi < 4; ++bi)
                    mm[ai][bi] = fmaf(av[ai], bv[bi], mm[ai][bi]);
        }
        // writes go to dst which nobody reads this iteration -> no pre-barrier
#pragma unroll
        for (int ai = 0; ai < 4; ++ai) {
            float4 w4;
            w4.x = mm[ai][0]; w4.y = mm[ai][1]; w4.z = mm[ai][2]; w4.w = mm[ai][3];
            *(float4*)&dst[(i0 + ai) * 64 + j0] = w4;
        }
#pragma unroll
        for (int ai = 0; ai < 4; ++ai)
#pragma unroll
            for (int bi = 0; bi < 4; ++bi) {
                pacc[ai][bi] = fmaf(PP[s + 2], mm[ai][bi], pacc[ai][bi]);
                qacc[ai][bi] = fmaf(QQ[s + 2], mm[ai][bi], qacc[ai][bi]);
            }
        __syncthreads();
        float* tmpp = src; src = dst; dst = tmpp;
    }

    // store P into A, Q into B
#pragma unroll
    for (int ai = 0; ai < 4; ++ai) {
        float4 wp, wq;
        wp.x = pacc[ai][0]; wp.y = pacc[ai][1]; wp.z = pacc[ai][2]; wp.w = pacc[ai][3];
        wq.x = qacc[ai][0]; wq.y = qacc[ai][1]; wq.z = qacc[ai][2]; wq.w = qacc[ai][3];
        *(float4*)&A[(i0 + ai) * 64 + j0] = wp;
        *(float4*)&B[(i0 + ai) * 64 + j0] = wq;
    }
    __syncthreads();

    // Gauss-Jordan: P X = Q  (P SPD -> no pivoting needed)
    const int gi   = t >> 2;  // row 0..63
    const int quad = t & 3;   // 0,1: A col halves; 2,3: B col halves
    for (int k = 0; k < 64; ++k) {
        const float rinv = 1.0f / A[k * 64 + k];
        __syncthreads();
        if (t < 64)       A[k * 64 + t] *= rinv;
        else if (t < 128) B[k * 64 + (t - 64)] *= rinv;
        const float f = (gi == k) ? 0.f : A[gi * 64 + k];  // rows != k untouched by normalize
        __syncthreads();
        if (gi != k) {
            if (quad < 2) {
                const int c0 = quad * 32;
#pragma unroll 8
                for (int c = 0; c < 32; ++c)
                    A[gi * 64 + c0 + c] -= f * A[k * 64 + c0 + c];
            } else {
                const int c0 = (quad - 2) * 32;
#pragma unroll 8
                for (int c = 0; c < 32; ++c)
                    B[gi * 64 + c0 + c] -= f * B[k * 64 + c0 + c];
            }
        }
        __syncthreads();
    }

    // fold weight / bias / mean
    const float invs = 1.0f / sqrtf(normM);
    if (t < 64) {
        float sm = 0.f;
        for (int j = 0; j < 64; ++j) sm += B[t * 64 + j] * mus[j];
        offv[g * NM + t] = bias[g * NM + t] - sm * invs * wgt[g * NM + t];
    }
#pragma unroll
    for (int k = 0; k < 16; ++k) {
        const int e = t + 256 * k;
        const int j = e >> 6, i = e & 63;
        Tt[g * 4096 + e] = B[i * 64 + j] * invs * wgt[g * NM + i];
    }
}

// ---------------------------------------------------------------------------
// Kernel 3: out = T @ x + off (per group), tile-staged GEMM.
// LDS x tile is [ch][pos] (b128 writes & reads, conflict-free).
// ---------------------------------------------------------------------------
__global__ __launch_bounds__(256) void apply_k(const float* __restrict__ x,
                                               const float* __restrict__ Tt,
                                               const float* __restrict__ offv,
                                               float* __restrict__ out) {
    __shared__ float xs[4096];
    __shared__ float Ts[4096];   // Ts[j*64+i] = T[i][j]
    __shared__ float offs[64];

    const int bid = blockIdx.x;
    const int g   = bid >> 7;
    const int blk = bid & 127;
    const int n   = blk >> 2;
    const int q   = blk & 3;
    const size_t base = ((size_t)(n * CHAN + g * NM)) * HWSZ + q * 1024;
    const float* xb = x + base;
    float* ob = out + base;

    const int t    = threadIdx.x;
    const int pos4 = t & 15, chb = t >> 4;
    const int ty   = t >> 4, tx = t & 15;
    const int i0   = ty * 4, p0 = tx * 4;

    const float* Tg = Tt + g * 4096;
#pragma unroll
    for (int r = 0; r < 16; ++r) Ts[t + 256 * r] = Tg[t + 256 * r];
    if (t < 64) offs[t] = offv[g * NM + t];
    __syncthreads();

    float offr[4];
#pragma unroll
    for (int ai = 0; ai < 4; ++ai) offr[ai] = offs[i0 + ai];

    for (int tt = 0; tt < 16; ++tt) {
        const float* xt = xb + tt * 64;
#pragma unroll
        for (int r = 0; r < 4; ++r) {
            const int ch = chb + 16 * r;
            const float4 v = *(const float4*)(xt + (size_t)ch * HWSZ + pos4 * 4);
            *(float4*)&xs[ch * 64 + pos4 * 4] = v;
        }
        __syncthreads();

        float acc[4][4];
#pragma unroll
        for (int ai = 0; ai < 4; ++ai)
#pragma unroll
            for (int pi = 0; pi < 4; ++pi) acc[ai][pi] = offr[ai];

#pragma unroll 16
        for (int j = 0; j < 64; ++j) {
            const float4 a4 = *(const float4*)&Ts[j * 64 + i0];
            const float4 b4 = *(const float4*)&xs[j * 64 + p0];
            const float av[4] = {a4.x, a4.y, a4.z, a4.w};
            const float bv[4] = {b4.x, b4.y, b4.z, b4.w};
#pragma unroll
            for (int ai = 0; ai < 4; ++ai)
#pragma unroll
                for (int pi = 0; pi < 4; ++pi)
                    acc[ai][pi] = fmaf(av[ai], bv[pi], acc[ai][pi]);
        }

#pragma unroll
        for (int ai = 0; ai < 4; ++ai) {
            float4 w4;
            w4.x = acc[ai][0]; w4.y = acc[ai][1]; w4.z = acc[ai][2]; w4.w = acc[ai][3];
            *(float4*)(ob + (size_t)(i0 + ai) * HWSZ + tt * 64 + p0) = w4;
        }
        __syncthreads();
    }
}

// ---------------------------------------------------------------------------
extern "C" void kernel_launch(void* const* d_in, const int* in_sizes, int n_in,
                              void* d_out, int out_size, void* d_ws, size_t ws_size,
                              hipStream_t stream) {
    const float* x    = (const float*)d_in[0];
    const float* wgt  = (const float*)d_in[1];
    const float* bias = (const float*)d_in[2];
    float* out = (float*)d_out;

    float* ws   = (float*)d_ws;
    float* gram = ws;            // 8*64*64 = 32768 floats
    float* sums = ws + 32768;    // 8*64    = 512
    float* Tt   = ws + 33280;    // 8*64*64 = 32768
    float* offv = ws + 66048;    // 8*64    = 512

    hipMemsetAsync(ws, 0, (32768 + 512) * sizeof(float), stream);
    gram_k<<<1024, 256, 0, stream>>>(x, gram, sums);
    solve_k<<<8, 256, 0, stream>>>(gram, sums, wgt, bias, Tt, offv);
    apply_k<<<1024, 256, 0, stream>>>(x, Tt, offv, out);
}

// Round 2
// 496.382 us; speedup vs baseline: 3.4053x; 3.4053x over previous
//
#include <hip/hip_runtime.h>

#define NBATCH 32
#define CHAN   512
#define HWSZ   4096
#define NG     8
#define NM     64
#define MTOT   (NBATCH * HWSZ)   // 131072 samples per channel
#define EPSC   0.01f

typedef _Float16 f16;
typedef _Float16 f16x8 __attribute__((ext_vector_type(8)));
typedef float    f32x4 __attribute__((ext_vector_type(4)));

#define MFMA16(a, b, c) __builtin_amdgcn_mfma_f32_16x16x32_f16(a, b, c, 0, 0, 0)

// ---------------------------------------------------------------------------
// Kernel 1: per-block partial Gram via f16 MFMA + per-channel partial sums.
// Grid 512 = 8 groups x 32 batch x 2 halves; block 256 (4 waves).
// LDS tile [64 ch][128 pos] f16, swizzle: half_off_in_row ^= (ch&7)<<3.
//  - staging writes: b128, uniform 8 lanes/bank-group (conflict-free)
//  - fragment reads: b128, uniform (conflict-free)
// For Gram, A-frag and B-frag layouts coincide: frag[rb] serves both roles.
// ---------------------------------------------------------------------------
__global__ __launch_bounds__(256) void gram_k(const float* __restrict__ x,
                                              float* __restrict__ gpart,
                                              float* __restrict__ spart) {
    __shared__ __align__(16) f16 tile[64 * 128];
    __shared__ float red[4][4096];

    const int bid  = blockIdx.x;     // 0..511
    const int g    = bid >> 6;
    const int n    = (bid >> 1) & 31;
    const int half = bid & 1;
    const float* xb = x + ((size_t)(n * CHAN + g * NM)) * HWSZ + half * 2048;

    const int t = threadIdx.x;
    const int w = t >> 6;            // wave 0..3
    const int l = t & 63;

    f32x4 acc[4][4];
#pragma unroll
    for (int i = 0; i < 4; ++i)
#pragma unroll
        for (int j = 0; j < 4; ++j) acc[i][j] = (f32x4){0.f, 0.f, 0.f, 0.f};
    float fsum[4] = {0.f, 0.f, 0.f, 0.f};

    for (int tt = 0; tt < 16; ++tt) {       // 16 tiles of 128 positions
        const float* xt = xb + tt * 128;
        // ---- stage f32 -> f16 into swizzled LDS ----
#pragma unroll
        for (int i = 0; i < 4; ++i) {
            const int p    = t + 256 * i;   // 0..1023
            const int ch   = p >> 4;        // = (t>>4) + 16*i
            const int off8 = (p & 15) * 8;  // 8 consecutive positions
            const float4 v0 = *(const float4*)(xt + (size_t)ch * HWSZ + off8);
            const float4 v1 = *(const float4*)(xt + (size_t)ch * HWSZ + off8 + 4);
            fsum[i] += (v0.x + v0.y) + (v0.z + v0.w) + (v1.x + v1.y) + (v1.z + v1.w);
            f16x8 hv;
            hv[0] = (f16)v0.x; hv[1] = (f16)v0.y; hv[2] = (f16)v0.z; hv[3] = (f16)v0.w;
            hv[4] = (f16)v1.x; hv[5] = (f16)v1.y; hv[6] = (f16)v1.z; hv[7] = (f16)v1.w;
            *(f16x8*)&tile[ch * 128 + (off8 ^ ((ch & 7) << 3))] = hv;
        }
        __syncthreads();

        // ---- fragments: wave w owns k-window [w*32, w*32+32) ----
        f16x8 frag[4];
#pragma unroll
        for (int rb = 0; rb < 4; ++rb) {
            const int ch = rb * 16 + (l & 15);
            const int k0 = w * 32 + (l >> 4) * 8;
            frag[rb] = *(const f16x8*)&tile[ch * 128 + (k0 ^ ((ch & 7) << 3))];
        }
#pragma unroll
        for (int i = 0; i < 4; ++i)
#pragma unroll
            for (int j = 0; j < 4; ++j)
                acc[i][j] = MFMA16(frag[i], frag[j], acc[i][j]);
        __syncthreads();
    }

    // ---- per-channel sums: reduce over the 16 lanes sharing a channel ----
#pragma unroll
    for (int i = 0; i < 4; ++i) {
        fsum[i] += __shfl_xor(fsum[i], 1);
        fsum[i] += __shfl_xor(fsum[i], 2);
        fsum[i] += __shfl_xor(fsum[i], 4);
        fsum[i] += __shfl_xor(fsum[i], 8);
    }
    if ((l & 15) == 0) {
        const int chb = t >> 4;   // 0..15
#pragma unroll
        for (int i = 0; i < 4; ++i)
            spart[(size_t)bid * 64 + chb + 16 * i] = fsum[i];
    }

    // ---- cross-wave accumulator reduce via LDS, write block partial ----
#pragma unroll
    for (int i = 0; i < 4; ++i)
#pragma unroll
        for (int j = 0; j < 4; ++j)
#pragma unroll
            for (int r = 0; r < 4; ++r) {
                const int row = i * 16 + (l >> 4) * 4 + r;
                const int col = j * 16 + (l & 15);
                red[w][row * 64 + col] = acc[i][j][r];
            }
    __syncthreads();
#pragma unroll
    for (int k = 0; k < 16; ++k) {
        const int e = t + 256 * k;
        gpart[(size_t)bid * 4096 + e] = (red[0][e] + red[1][e]) + (red[2][e] + red[3][e]);
    }
}

// ---------------------------------------------------------------------------
// Kernel 1b: sum 64 partials per group. Grid 128 = 8 groups x 16 chunks.
// ---------------------------------------------------------------------------
__global__ __launch_bounds__(256) void reduce_k(const float* __restrict__ gpart,
                                                const float* __restrict__ spart,
                                                float* __restrict__ gram,
                                                float* __restrict__ sums) {
    const int g = blockIdx.x >> 4, c = blockIdx.x & 15;
    const int t = threadIdx.x;
    float s = 0.f;
    for (int p = 0; p < 64; ++p)
        s += gpart[((size_t)(g * 64 + p)) * 4096 + c * 256 + t];
    gram[g * 4096 + c * 256 + t] = s;
    if (c == 0 && t < 64) {
        float ss = 0.f;
        for (int p = 0; p < 64; ++p) ss += spart[(size_t)(g * 64 + p) * 64 + t];
        sums[g * 64 + t] = ss;
    }
}

// ---------------------------------------------------------------------------
// Kernel 2: per-group inverse matrix sqrt ([5/5] Pade + Gauss-Jordan).
// Emits T (f16, row-major [oc][ic], = S*w) and off (f32, bias - S*w*mu).
// ---------------------------------------------------------------------------
__global__ __launch_bounds__(256) void solve_k(const float* __restrict__ gram,
                                               const float* __restrict__ sums,
                                               const float* __restrict__ wgt,
                                               const float* __restrict__ bias,
                                               f16* __restrict__ Tf,
                                               float* __restrict__ offv) {
    __shared__ float A[4096];
    __shared__ float B[4096];
    __shared__ float Cc[4096];
    __shared__ float mus[64];
    __shared__ float red[4];

    const int g = blockIdx.x, t = threadIdx.x;
    const float* gg = gram + g * 4096;

    if (t < 64) mus[t] = sums[g * NM + t] * (1.0f / MTOT);
    __syncthreads();

    float covv[16];
    float loc = 0.f;
#pragma unroll
    for (int k = 0; k < 16; ++k) {
        const int e = t + 256 * k;
        const int i = e >> 6, j = e & 63;
        float cv = gg[e] * (1.0f / MTOT) - mus[i] * mus[j] + (i == j ? EPSC : 0.f);
        covv[k] = cv;
        loc += cv * cv;
    }
#pragma unroll
    for (int o = 32; o > 0; o >>= 1) loc += __shfl_down(loc, o);
    if ((t & 63) == 0) red[t >> 6] = loc;
    __syncthreads();
    const float normM = sqrtf(red[0] + red[1] + red[2] + red[3]);
    const float ninv  = 1.0f / normM;

#pragma unroll
    for (int k = 0; k < 16; ++k) {
        const int e = t + 256 * k;
        const int i = e >> 6, j = e & 63;
        const float pa = (i == j ? 1.f : 0.f) - covv[k] * ninv;
        A[e] = pa;
        B[e] = pa;
    }
    __syncthreads();

    const int ty = t >> 4, tx = t & 15;
    const int i0 = ty * 4, j0 = tx * 4;

    const float PP[6] = {1.f, -2.75f, 2.75f, -1.203125f, 0.21484375f, -0.0107421875f};
    const float QQ[6] = {1.f, -2.25f, 1.75f, -0.546875f, 0.05859375f, -0.0009765625f};

    float pacc[4][4], qacc[4][4];
#pragma unroll
    for (int ai = 0; ai < 4; ++ai)
#pragma unroll
        for (int bi = 0; bi < 4; ++bi) {
            const int i = i0 + ai, j = j0 + bi;
            const float pa = A[i * 64 + j];
            const float id = (i == j) ? 1.f : 0.f;
            pacc[ai][bi] = PP[0] * id + PP[1] * pa;
            qacc[ai][bi] = QQ[0] * id + QQ[1] * pa;
        }

    float* src = B;
    float* dst = Cc;
    for (int s = 0; s < 4; ++s) {
        float mm[4][4];
#pragma unroll
        for (int ai = 0; ai < 4; ++ai)
#pragma unroll
            for (int bi = 0; bi < 4; ++bi) mm[ai][bi] = 0.f;
        for (int kk = 0; kk < 64; ++kk) {
            const float4 a4 = *(const float4*)&src[kk * 64 + i0];
            const float4 b4 = *(const float4*)&A[kk * 64 + j0];
            const float av[4] = {a4.x, a4.y, a4.z, a4.w};
            const float bv[4] = {b4.x, b4.y, b4.z, b4.w};
#pragma unroll
            for (int ai = 0; ai < 4; ++ai)
#pragma unroll
                for (int bi = 0; bi < 4; ++bi)
                    mm[ai][bi] = fmaf(av[ai], bv[bi], mm[ai][bi]);
        }
#pragma unroll
        for (int ai = 0; ai < 4; ++ai) {
            float4 w4;
            w4.x = mm[ai][0]; w4.y = mm[ai][1]; w4.z = mm[ai][2]; w4.w = mm[ai][3];
            *(float4*)&dst[(i0 + ai) * 64 + j0] = w4;
        }
#pragma unroll
        for (int ai = 0; ai < 4; ++ai)
#pragma unroll
            for (int bi = 0; bi < 4; ++bi) {
                pacc[ai][bi] = fmaf(PP[s + 2], mm[ai][bi], pacc[ai][bi]);
                qacc[ai][bi] = fmaf(QQ[s + 2], mm[ai][bi], qacc[ai][bi]);
            }
        __syncthreads();
        float* tmpp = src; src = dst; dst = tmpp;
    }

#pragma unroll
    for (int ai = 0; ai < 4; ++ai) {
        float4 wp, wq;
        wp.x = pacc[ai][0]; wp.y = pacc[ai][1]; wp.z = pacc[ai][2]; wp.w = pacc[ai][3];
        wq.x = qacc[ai][0]; wq.y = qacc[ai][1]; wq.z = qacc[ai][2]; wq.w = qacc[ai][3];
        *(float4*)&A[(i0 + ai) * 64 + j0] = wp;
        *(float4*)&B[(i0 + ai) * 64 + j0] = wq;
    }
    __syncthreads();

    const int gi   = t >> 2;
    const int quad = t & 3;
    for (int k = 0; k < 64; ++k) {
        const float rinv = 1.0f / A[k * 64 + k];
        __syncthreads();
        if (t < 64)       A[k * 64 + t] *= rinv;
        else if (t < 128) B[k * 64 + (t - 64)] *= rinv;
        const float f = (gi == k) ? 0.f : A[gi * 64 + k];
        __syncthreads();
        if (gi != k) {
            if (quad < 2) {
                const int c0 = quad * 32;
#pragma unroll 8
                for (int c = 0; c < 32; ++c)
                    A[gi * 64 + c0 + c] -= f * A[k * 64 + c0 + c];
            } else {
                const int c0 = (quad - 2) * 32;
#pragma unroll 8
                for (int c = 0; c < 32; ++c)
                    B[gi * 64 + c0 + c] -= f * B[k * 64 + c0 + c];
            }
        }
        __syncthreads();
    }

    const float invs = 1.0f / sqrtf(normM);
    if (t < 64) {
        float sm = 0.f;
        for (int j = 0; j < 64; ++j) sm += B[t * 64 + j] * mus[j];
        offv[g * NM + t] = bias[g * NM + t] - sm * invs * wgt[g * NM + t];
    }
#pragma unroll
    for (int k = 0; k < 16; ++k) {
        const int e = t + 256 * k;      // e = i*64 + j (row-major [oc][ic])
        const int i = e >> 6;
        Tf[(size_t)g * 4096 + e] = (f16)(B[e] * invs * wgt[g * NM + i]);
    }
}

// ---------------------------------------------------------------------------
// Kernel 3: out = T @ x + off via f16 MFMA.
// X staged transposed [128 pos][64 ch] f16; swizzle ch ^= ((pos^(pos>>3))&7)<<3
// makes both the pos-strided u16 staging writes and the ch-contiguous b128
// fragment reads conflict-free. T staged [oc][ic] with ch-row swizzle.
// ---------------------------------------------------------------------------
__global__ __launch_bounds__(256) void apply_k(const float* __restrict__ x,
                                               const f16* __restrict__ Tf,
                                               const float* __restrict__ offv,
                                               float* __restrict__ out) {
    __shared__ __align__(16) f16 xs[128 * 64];
    __shared__ __align__(16) f16 Ts[4096];
    __shared__ float offs[64];

    const int bid  = blockIdx.x;     // 0..511
    const int g    = bid >> 6;
    const int n    = (bid >> 1) & 31;
    const int half = bid & 1;
    const size_t base = ((size_t)(n * CHAN + g * NM)) * HWSZ + half * 2048;
    const float* xb = x + base;
    float* ob = out + base;

    const int t = threadIdx.x;
    const int w = t >> 6;
    const int l = t & 63;

    // stage T (swizzled) and off
#pragma unroll
    for (int i = 0; i < 2; ++i) {
        const int c   = t + 256 * i;      // 0..511 chunks of 8 halves
        const int oc  = c >> 3;
        const int icb = (c & 7) * 8;
        const f16x8 v = *(const f16x8*)&Tf[(size_t)g * 4096 + oc * 64 + icb];
        *(f16x8*)&Ts[oc * 64 + (icb ^ ((oc & 7) << 3))] = v;
    }
    if (t < 64) offs[t] = offv[g * NM + t];
    __syncthreads();

    // A fragments (T) — constant per block, load once
    f16x8 afrag[2];
#pragma unroll
    for (int c = 0; c < 2; ++c) {
        const int oc = w * 16 + (l & 15);
        const int k0 = c * 32 + (l >> 4) * 8;
        afrag[c] = *(const f16x8*)&Ts[oc * 64 + (k0 ^ ((oc & 7) << 3))];
    }
    float offr[4];
#pragma unroll
    for (int r = 0; r < 4; ++r) offr[r] = offs[w * 16 + (l >> 4) * 4 + r];

    for (int tt = 0; tt < 16; ++tt) {
        const float* xt = xb + tt * 128;
        __syncthreads();
        // ---- stage transposed f32 -> f16 ----
#pragma unroll
        for (int i = 0; i < 4; ++i) {
            const int p    = t + 256 * i;
            const int ch   = p >> 4;
            const int off8 = (p & 15) * 8;
            const float4 v0 = *(const float4*)(xt + (size_t)ch * HWSZ + off8);
            const float4 v1 = *(const float4*)(xt + (size_t)ch * HWSZ + off8 + 4);
            f16 h[8];
            h[0] = (f16)v0.x; h[1] = (f16)v0.y; h[2] = (f16)v0.z; h[3] = (f16)v0.w;
            h[4] = (f16)v1.x; h[5] = (f16)v1.y; h[6] = (f16)v1.z; h[7] = (f16)v1.w;
#pragma unroll
            for (int j = 0; j < 8; ++j) {
                const int pos = off8 + j;
                xs[pos * 64 + (ch ^ (((pos ^ (pos >> 3)) & 7) << 3))] = h[j];
            }
        }
        __syncthreads();

        // ---- compute: wave w owns output-channel block w ----
#pragma unroll
        for (int pb = 0; pb < 8; ++pb) {
            f32x4 acc;
            acc[0] = offr[0]; acc[1] = offr[1]; acc[2] = offr[2]; acc[3] = offr[3];
            const int pos = pb * 16 + (l & 15);
            const int swz = ((pos ^ (pos >> 3)) & 7) << 3;
#pragma unroll
            for (int c = 0; c < 2; ++c) {
                const int k0 = c * 32 + (l >> 4) * 8;
                const f16x8 bfrag = *(const f16x8*)&xs[pos * 64 + (k0 ^ swz)];
                acc = MFMA16(afrag[c], bfrag, acc);
            }
            const int posg = tt * 128 + pb * 16 + (l & 15);
#pragma unroll
            for (int r = 0; r < 4; ++r) {
                const int oc = w * 16 + (l >> 4) * 4 + r;
                ob[(size_t)oc * HWSZ + posg] = acc[r];
            }
        }
    }
}

// ---------------------------------------------------------------------------
extern "C" void kernel_launch(void* const* d_in, const int* in_sizes, int n_in,
                              void* d_out, int out_size, void* d_ws, size_t ws_size,
                              hipStream_t stream) {
    const float* x    = (const float*)d_in[0];
    const float* wgt  = (const float*)d_in[1];
    const float* bias = (const float*)d_in[2];
    float* out = (float*)d_out;

    float* ws    = (float*)d_ws;
    float* gpart = ws;                  // 512*4096 = 2097152 floats
    float* spart = ws + 2097152;        // 512*64   = 32768
    float* gram  = ws + 2129920;        // 8*4096   = 32768
    float* sums  = ws + 2162688;        // 512
    float* offv  = ws + 2163200;        // 512
    f16*   Tf    = (f16*)(ws + 2163712);// 8*4096 halves (16384 float slots)

    gram_k  <<<512, 256, 0, stream>>>(x, gpart, spart);
    reduce_k<<<128, 256, 0, stream>>>(gpart, spart, gram, sums);
    solve_k <<<8,   256, 0, stream>>>(gram, sums, wgt, bias, Tf, offv);
    apply_k <<<512, 256, 0, stream>>>(x, Tf, offv, out);
}

// Round 3
// 307.250 us; speedup vs baseline: 5.5015x; 1.6156x over previous
//
#include <hip/hip_runtime.h>

#define NBATCH 32
#define CHAN   512
#define HWSZ   4096
#define NG     8
#define NM     64
#define MTOT   (NBATCH * HWSZ)   // 131072 samples per channel
#define EPSC   0.01f
#define P68    68                // padded LDS row stride (68 mod 32 = 4 -> <=2-way banks)

typedef _Float16 f16;
typedef _Float16 f16x8 __attribute__((ext_vector_type(8)));
typedef float    f32x4 __attribute__((ext_vector_type(4)));

#define MFMA16(a, b, c) __builtin_amdgcn_mfma_f32_16x16x32_f16(a, b, c, 0, 0, 0)

// ---------------------------------------------------------------------------
// Kernel 1: per-block partial Gram via f16 MFMA + per-channel partial sums.
// (unchanged from round 2 — passing, not current bottleneck)
// ---------------------------------------------------------------------------
__global__ __launch_bounds__(256) void gram_k(const float* __restrict__ x,
                                              float* __restrict__ gpart,
                                              float* __restrict__ spart) {
    __shared__ __align__(16) f16 tile[64 * 128];
    __shared__ float red[4][4096];

    const int bid  = blockIdx.x;     // 0..511
    const int g    = bid >> 6;
    const int n    = (bid >> 1) & 31;
    const int half = bid & 1;
    const float* xb = x + ((size_t)(n * CHAN + g * NM)) * HWSZ + half * 2048;

    const int t = threadIdx.x;
    const int w = t >> 6;            // wave 0..3
    const int l = t & 63;

    f32x4 acc[4][4];
#pragma unroll
    for (int i = 0; i < 4; ++i)
#pragma unroll
        for (int j = 0; j < 4; ++j) acc[i][j] = (f32x4){0.f, 0.f, 0.f, 0.f};
    float fsum[4] = {0.f, 0.f, 0.f, 0.f};

    for (int tt = 0; tt < 16; ++tt) {
        const float* xt = xb + tt * 128;
#pragma unroll
        for (int i = 0; i < 4; ++i) {
            const int p    = t + 256 * i;
            const int ch   = p >> 4;
            const int off8 = (p & 15) * 8;
            const float4 v0 = *(const float4*)(xt + (size_t)ch * HWSZ + off8);
            const float4 v1 = *(const float4*)(xt + (size_t)ch * HWSZ + off8 + 4);
            fsum[i] += (v0.x + v0.y) + (v0.z + v0.w) + (v1.x + v1.y) + (v1.z + v1.w);
            f16x8 hv;
            hv[0] = (f16)v0.x; hv[1] = (f16)v0.y; hv[2] = (f16)v0.z; hv[3] = (f16)v0.w;
            hv[4] = (f16)v1.x; hv[5] = (f16)v1.y; hv[6] = (f16)v1.z; hv[7] = (f16)v1.w;
            *(f16x8*)&tile[ch * 128 + (off8 ^ ((ch & 7) << 3))] = hv;
        }
        __syncthreads();

        f16x8 frag[4];
#pragma unroll
        for (int rb = 0; rb < 4; ++rb) {
            const int ch = rb * 16 + (l & 15);
            const int k0 = w * 32 + (l >> 4) * 8;
            frag[rb] = *(const f16x8*)&tile[ch * 128 + (k0 ^ ((ch & 7) << 3))];
        }
#pragma unroll
        for (int i = 0; i < 4; ++i)
#pragma unroll
            for (int j = 0; j < 4; ++j)
                acc[i][j] = MFMA16(frag[i], frag[j], acc[i][j]);
        __syncthreads();
    }

#pragma unroll
    for (int i = 0; i < 4; ++i) {
        fsum[i] += __shfl_xor(fsum[i], 1);
        fsum[i] += __shfl_xor(fsum[i], 2);
        fsum[i] += __shfl_xor(fsum[i], 4);
        fsum[i] += __shfl_xor(fsum[i], 8);
    }
    if ((l & 15) == 0) {
        const int chb = t >> 4;
#pragma unroll
        for (int i = 0; i < 4; ++i)
            spart[(size_t)bid * 64 + chb + 16 * i] = fsum[i];
    }

#pragma unroll
    for (int i = 0; i < 4; ++i)
#pragma unroll
        for (int j = 0; j < 4; ++j)
#pragma unroll
            for (int r = 0; r < 4; ++r) {
                const int row = i * 16 + (l >> 4) * 4 + r;
                const int col = j * 16 + (l & 15);
                red[w][row * 64 + col] = acc[i][j][r];
            }
    __syncthreads();
#pragma unroll
    for (int k = 0; k < 16; ++k) {
        const int e = t + 256 * k;
        gpart[(size_t)bid * 4096 + e] = (red[0][e] + red[1][e]) + (red[2][e] + red[3][e]);
    }
}

// ---------------------------------------------------------------------------
// Kernel 1b: sum 64 partials per group. Grid 128 = 8 groups x 16 chunks.
// ---------------------------------------------------------------------------
__global__ __launch_bounds__(256) void reduce_k(const float* __restrict__ gpart,
                                                const float* __restrict__ spart,
                                                float* __restrict__ gram,
                                                float* __restrict__ sums) {
    const int g = blockIdx.x >> 4, c = blockIdx.x & 15;
    const int t = threadIdx.x;
    float s = 0.f;
    for (int p = 0; p < 64; ++p)
        s += gpart[((size_t)(g * 64 + p)) * 4096 + c * 256 + t];
    gram[g * 4096 + c * 256 + t] = s;
    if (c == 0 && t < 64) {
        float ss = 0.f;
        for (int p = 0; p < 64; ++p) ss += spart[(size_t)(g * 64 + p) * 64 + t];
        sums[g * 64 + t] = ss;
    }
}

// ---------------------------------------------------------------------------
// Kernel 2: per-group inverse matrix sqrt ([5/5] Pade + Gauss-Jordan).
// Rewritten: stride-68 padded LDS (<=2-way banks), 1-barrier/iter GJ with
// double-buffered pivot row/column/diag. Emits T (f16, [oc][ic], = S*w) and
// off (f32, bias - S*w*mu).
// ---------------------------------------------------------------------------
__global__ __launch_bounds__(256) void solve_k(const float* __restrict__ gram,
                                               const float* __restrict__ sums,
                                               const float* __restrict__ wgt,
                                               const float* __restrict__ bias,
                                               f16* __restrict__ Tf,
                                               float* __restrict__ offv) {
    __shared__ __align__(16) float A[64 * P68];   // p_app, later P (GJ-reduced)
    __shared__ __align__(16) float B[64 * P68];   // p_hat ping, later Q -> P^{-1}Q
    __shared__ __align__(16) float Cc[64 * P68];  // p_hat pong
    __shared__ __align__(16) float prow[2][128];  // pivot row (A cols | B cols)
    __shared__ float pcol[2][64];                 // pivot column of A
    __shared__ float pds[2];                      // pivot diagonal
    __shared__ float mus[64];
    __shared__ float red[4];

    const int g = blockIdx.x, t = threadIdx.x;
    const float* gg = gram + g * 4096;

    if (t < 64) mus[t] = sums[g * NM + t] * (1.0f / MTOT);
    __syncthreads();

    // covariance + Frobenius norm
    float covv[16];
    float loc = 0.f;
#pragma unroll
    for (int k = 0; k < 16; ++k) {
        const int e = t + 256 * k;
        const int i = e >> 6, j = e & 63;
        float cv = gg[e] * (1.0f / MTOT) - mus[i] * mus[j] + (i == j ? EPSC : 0.f);
        covv[k] = cv;
        loc += cv * cv;
    }
#pragma unroll
    for (int o = 32; o > 0; o >>= 1) loc += __shfl_down(loc, o);
    if ((t & 63) == 0) red[t >> 6] = loc;
    __syncthreads();
    const float normM = sqrtf(red[0] + red[1] + red[2] + red[3]);
    const float ninv  = 1.0f / normM;

#pragma unroll
    for (int k = 0; k < 16; ++k) {
        const int e = t + 256 * k;
        const int i = e >> 6, j = e & 63;
        const float pa = (i == j ? 1.f : 0.f) - covv[k] * ninv;
        A[i * P68 + j] = pa;
        B[i * P68 + j] = pa;
    }
    __syncthreads();

    const int ty = t >> 4, tx = t & 15;
    const int i0 = ty * 4, j0 = tx * 4;

    const float PP[6] = {1.f, -2.75f, 2.75f, -1.203125f, 0.21484375f, -0.0107421875f};
    const float QQ[6] = {1.f, -2.25f, 1.75f, -0.546875f, 0.05859375f, -0.0009765625f};

    float pacc[4][4], qacc[4][4];
#pragma unroll
    for (int ai = 0; ai < 4; ++ai)
#pragma unroll
        for (int bi = 0; bi < 4; ++bi) {
            const int i = i0 + ai, j = j0 + bi;
            const float pa = A[i * P68 + j];
            const float id = (i == j) ? 1.f : 0.f;
            pacc[ai][bi] = PP[0] * id + PP[1] * pa;
            qacc[ai][bi] = QQ[0] * id + QQ[1] * pa;
        }

    // Pade polynomial: 4 symmetric 64^3 matmuls (p_hat^{s+2})
    float* src = B;
    float* dst = Cc;
    for (int s = 0; s < 4; ++s) {
        float mm[4][4];
#pragma unroll
        for (int ai = 0; ai < 4; ++ai)
#pragma unroll
            for (int bi = 0; bi < 4; ++bi) mm[ai][bi] = 0.f;
        for (int kk = 0; kk < 64; ++kk) {
            const float4 a4 = *(const float4*)&src[kk * P68 + i0];
            const float4 b4 = *(const float4*)&A[kk * P68 + j0];
            const float av[4] = {a4.x, a4.y, a4.z, a4.w};
            const float bv[4] = {b4.x, b4.y, b4.z, b4.w};
#pragma unroll
            for (int ai = 0; ai < 4; ++ai)
#pragma unroll
                for (int bi = 0; bi < 4; ++bi)
                    mm[ai][bi] = fmaf(av[ai], bv[bi], mm[ai][bi]);
        }
#pragma unroll
        for (int ai = 0; ai < 4; ++ai) {
            float4 w4;
            w4.x = mm[ai][0]; w4.y = mm[ai][1]; w4.z = mm[ai][2]; w4.w = mm[ai][3];
            *(float4*)&dst[(i0 + ai) * P68 + j0] = w4;
        }
#pragma unroll
        for (int ai = 0; ai < 4; ++ai)
#pragma unroll
            for (int bi = 0; bi < 4; ++bi) {
                pacc[ai][bi] = fmaf(PP[s + 2], mm[ai][bi], pacc[ai][bi]);
                qacc[ai][bi] = fmaf(QQ[s + 2], mm[ai][bi], qacc[ai][bi]);
            }
        __syncthreads();
        float* tmpp = src; src = dst; dst = tmpp;
    }

    // store P into A, Q into B
#pragma unroll
    for (int ai = 0; ai < 4; ++ai) {
        float4 wp, wq;
        wp.x = pacc[ai][0]; wp.y = pacc[ai][1]; wp.z = pacc[ai][2]; wp.w = pacc[ai][3];
        wq.x = qacc[ai][0]; wq.y = qacc[ai][1]; wq.z = qacc[ai][2]; wq.w = qacc[ai][3];
        *(float4*)&A[(i0 + ai) * P68 + j0] = wp;
        *(float4*)&B[(i0 + ai) * P68 + j0] = wq;
    }
    __syncthreads();

    // ---- Gauss-Jordan: P X = Q, row-distributed, 1 barrier per pivot ----
    // thread t: row gi = t>>2, section quad = t&3
    //   quad 0: A[gi][0:32)   quad 1: A[gi][32:64)
    //   quad 2: B[gi][0:32)   quad 3: B[gi][32:64)
    const int gi   = t >> 2;
    const int quad = t & 3;
    float* own = (quad < 2) ? &A[gi * P68 + quad * 32]
                            : &B[gi * P68 + (quad - 2) * 32];

    // prologue: publish pivot data for k=0
    if (gi == 0) {
#pragma unroll
        for (int c4 = 0; c4 < 8; ++c4)
            *(float4*)&prow[0][quad * 32 + c4 * 4] = *(const float4*)&own[c4 * 4];
    }
    if (quad == 0) pcol[0][gi] = A[gi * P68];
    if (t == 0)    pds[0] = A[0];
    __syncthreads();

    for (int k = 0; k < 64; ++k) {
        const int buf = k & 1, nbuf = buf ^ 1;
        const float rinv = 1.0f / pds[buf];
        if (gi == k) {
#pragma unroll
            for (int c4 = 0; c4 < 8; ++c4) {
                float4 v = *(float4*)&own[c4 * 4];
                v.x *= rinv; v.y *= rinv; v.z *= rinv; v.w *= rinv;
                *(float4*)&own[c4 * 4] = v;
            }
        } else {
            const float fm = pcol[buf][gi] * rinv;
#pragma unroll
            for (int c4 = 0; c4 < 8; ++c4) {
                float4 v = *(float4*)&own[c4 * 4];
                const float4 p = *(const float4*)&prow[buf][quad * 32 + c4 * 4];
                v.x = fmaf(-fm, p.x, v.x);
                v.y = fmaf(-fm, p.y, v.y);
                v.z = fmaf(-fm, p.z, v.z);
                v.w = fmaf(-fm, p.w, v.w);
                *(float4*)&own[c4 * 4] = v;
            }
        }
        if (k < 63) {
            const int kn = k + 1;
            // publish next pivot row (row kn is fully updated by its owners above)
            if (gi == kn) {
#pragma unroll
                for (int c4 = 0; c4 < 8; ++c4)
                    *(float4*)&prow[nbuf][quad * 32 + c4 * 4] = *(const float4*)&own[c4 * 4];
                if (quad == (kn >> 5)) pds[nbuf] = A[kn * P68 + kn];  // own just-written value
            }
            // publish next pivot column (owner quad reads back its own writes)
            if (quad == (kn >> 5)) pcol[nbuf][gi] = A[gi * P68 + kn];
        }
        __syncthreads();
    }

    // ---- fold weight / bias / mean (B now holds X = P^{-1} Q) ----
    const float invs = 1.0f / sqrtf(normM);
    if (t < 64) {
        float sm = 0.f;
        for (int j = 0; j < 64; ++j) sm += B[t * P68 + j] * mus[j];
        offv[g * NM + t] = bias[g * NM + t] - sm * invs * wgt[g * NM + t];
    }
#pragma unroll
    for (int k = 0; k < 16; ++k) {
        const int e = t + 256 * k;      // e = i*64 + j (row-major [oc][ic])
        const int i = e >> 6, j = e & 63;
        Tf[(size_t)g * 4096 + e] = (f16)(B[i * P68 + j] * invs * wgt[g * NM + i]);
    }
}

// ---------------------------------------------------------------------------
// Kernel 3: out = T @ x + off via f16 MFMA. (unchanged from round 2)
// ---------------------------------------------------------------------------
__global__ __launch_bounds__(256) void apply_k(const float* __restrict__ x,
                                               const f16* __restrict__ Tf,
                                               const float* __restrict__ offv,
                                               float* __restrict__ out) {
    __shared__ __align__(16) f16 xs[128 * 64];
    __shared__ __align__(16) f16 Ts[4096];
    __shared__ float offs[64];

    const int bid  = blockIdx.x;
    const int g    = bid >> 6;
    const int n    = (bid >> 1) & 31;
    const int half = bid & 1;
    const size_t base = ((size_t)(n * CHAN + g * NM)) * HWSZ + half * 2048;
    const float* xb = x + base;
    float* ob = out + base;

    const int t = threadIdx.x;
    const int w = t >> 6;
    const int l = t & 63;

#pragma unroll
    for (int i = 0; i < 2; ++i) {
        const int c   = t + 256 * i;
        const int oc  = c >> 3;
        const int icb = (c & 7) * 8;
        const f16x8 v = *(const f16x8*)&Tf[(size_t)g * 4096 + oc * 64 + icb];
        *(f16x8*)&Ts[oc * 64 + (icb ^ ((oc & 7) << 3))] = v;
    }
    if (t < 64) offs[t] = offv[g * NM + t];
    __syncthreads();

    f16x8 afrag[2];
#pragma unroll
    for (int c = 0; c < 2; ++c) {
        const int oc = w * 16 + (l & 15);
        const int k0 = c * 32 + (l >> 4) * 8;
        afrag[c] = *(const f16x8*)&Ts[oc * 64 + (k0 ^ ((oc & 7) << 3))];
    }
    float offr[4];
#pragma unroll
    for (int r = 0; r < 4; ++r) offr[r] = offs[w * 16 + (l >> 4) * 4 + r];

    for (int tt = 0; tt < 16; ++tt) {
        const float* xt = xb + tt * 128;
        __syncthreads();
#pragma unroll
        for (int i = 0; i < 4; ++i) {
            const int p    = t + 256 * i;
            const int ch   = p >> 4;
            const int off8 = (p & 15) * 8;
            const float4 v0 = *(const float4*)(xt + (size_t)ch * HWSZ + off8);
            const float4 v1 = *(const float4*)(xt + (size_t)ch * HWSZ + off8 + 4);
            f16 h[8];
            h[0] = (f16)v0.x; h[1] = (f16)v0.y; h[2] = (f16)v0.z; h[3] = (f16)v0.w;
            h[4] = (f16)v1.x; h[5] = (f16)v1.y; h[6] = (f16)v1.z; h[7] = (f16)v1.w;
#pragma unroll
            for (int j = 0; j < 8; ++j) {
                const int pos = off8 + j;
                xs[pos * 64 + (ch ^ (((pos ^ (pos >> 3)) & 7) << 3))] = h[j];
            }
        }
        __syncthreads();

#pragma unroll
        for (int pb = 0; pb < 8; ++pb) {
            f32x4 acc;
            acc[0] = offr[0]; acc[1] = offr[1]; acc[2] = offr[2]; acc[3] = offr[3];
            const int pos = pb * 16 + (l & 15);
            const int swz = ((pos ^ (pos >> 3)) & 7) << 3;
#pragma unroll
            for (int c = 0; c < 2; ++c) {
                const int k0 = c * 32 + (l >> 4) * 8;
                const f16x8 bfrag = *(const f16x8*)&xs[pos * 64 + (k0 ^ swz)];
                acc = MFMA16(afrag[c], bfrag, acc);
            }
            const int posg = tt * 128 + pb * 16 + (l & 15);
#pragma unroll
            for (int r = 0; r < 4; ++r) {
                const int oc = w * 16 + (l >> 4) * 4 + r;
                ob[(size_t)oc * HWSZ + posg] = acc[r];
            }
        }
    }
}

// ---------------------------------------------------------------------------
extern "C" void kernel_launch(void* const* d_in, const int* in_sizes, int n_in,
                              void* d_out, int out_size, void* d_ws, size_t ws_size,
                              hipStream_t stream) {
    const float* x    = (const float*)d_in[0];
    const float* wgt  = (const float*)d_in[1];
    const float* bias = (const float*)d_in[2];
    float* out = (float*)d_out;

    float* ws    = (float*)d_ws;
    float* gpart = ws;                  // 512*4096 = 2097152 floats
    float* spart = ws + 2097152;        // 512*64   = 32768
    float* gram  = ws + 2129920;        // 8*4096   = 32768
    float* sums  = ws + 2162688;        // 512
    float* offv  = ws + 2163200;        // 512
    f16*   Tf    = (f16*)(ws + 2163712);// 8*4096 halves

    gram_k  <<<512, 256, 0, stream>>>(x, gpart, spart);
    reduce_k<<<128, 256, 0, stream>>>(gpart, spart, gram, sums);
    solve_k <<<8,   256, 0, stream>>>(gram, sums, wgt, bias, Tf, offv);
    apply_k <<<512, 256, 0, stream>>>(x, Tf, offv, out);
}